// Round 1
// baseline (301.795 us; speedup 1.0000x reference)
//
#include <hip/hip_runtime.h>
#include <cstdint>
#include <cstddef>

#define IN_CH 768
#define FH 14
#define FW 14
#define NPOS 196         // 14*14
#define NA 9
#define NANCH 1764       // 196*9
#define K1 1000
#define TOPK_N 300
#define CSPLIT 8
#define OPB 8
#define CPB (IN_CH / CSPLIT)   // 96
#define BBOX_CLIP 4.135166556742356f
#define IMG_W 224.0f
#define IMG_H 224.0f

// ---------- helpers ----------
__device__ __forceinline__ uint32_t f2sort(float f) {
    uint32_t b = __float_as_uint(f);
    return (b & 0x80000000u) ? ~b : (b | 0x80000000u);
}
__device__ __forceinline__ float sort2f(uint32_t s) {
    uint32_t b = (s & 0x80000000u) ? (s & 0x7fffffffu) : ~s;
    return __uint_as_float(b);
}

// ---------- kernel 1: 3x3 conv (split-K partials, deterministic) ----------
// grid = (IN_CH/OPB) * CSPLIT = 96*8 = 768 blocks, 256 threads
__global__ __launch_bounds__(256) void k_conv(const float* __restrict__ feature,
                                              const float* __restrict__ w_conv,
                                              float* __restrict__ xpart) {
    __shared__ float plane[256];   // 16x16, zero border
    const int bx  = blockIdx.x;
    const int cs  = bx & (CSPLIT - 1);
    const int ob  = bx / CSPLIT;
    const int o0  = ob * OPB;
    const int tid = threadIdx.x;

    const int py = tid >> 4, px = tid & 15;
    const bool inr = (py >= 1 && py <= 14 && px >= 1 && px <= 14);
    const int fidx = (py - 1) * FW + (px - 1);

    const int p = tid;                  // position if < 196
    const int y = p / FW, x = p % FW;
    const int base = (y + 1) * 16 + (x + 1);

    float acc[OPB];
#pragma unroll
    for (int i = 0; i < OPB; i++) acc[i] = 0.f;

    const int c0 = cs * CPB;
    float v = inr ? feature[IN_CH + (size_t)c0 * NPOS + fidx] : 0.f;

    for (int cc = 0; cc < CPB; cc++) {
        const int c = c0 + cc;
        __syncthreads();
        plane[tid] = v;
        __syncthreads();
        if (cc + 1 < CPB)
            v = inr ? feature[IN_CH + (size_t)(c + 1) * NPOS + fidx] : 0.f;
        if (p < NPOS) {
            const float r0 = plane[base - 17], r1 = plane[base - 16], r2 = plane[base - 15];
            const float r3 = plane[base - 1],  r4 = plane[base],      r5 = plane[base + 1];
            const float r6 = plane[base + 15], r7 = plane[base + 16], r8 = plane[base + 17];
            const float* wp = w_conv + ((size_t)o0 * IN_CH + c) * 9;
#pragma unroll
            for (int oo = 0; oo < OPB; oo++) {
                const float* w = wp + (size_t)oo * IN_CH * 9;
                acc[oo] += r0 * w[0] + r1 * w[1] + r2 * w[2]
                         + r3 * w[3] + r4 * w[4] + r5 * w[5]
                         + r6 * w[6] + r7 * w[7] + r8 * w[8];
            }
        }
    }
    if (p < NPOS) {
#pragma unroll
        for (int oo = 0; oo < OPB; oo++)
            xpart[((size_t)cs * IN_CH + (o0 + oo)) * NPOS + p] = acc[oo];
    }
}

// ---------- kernel 2: reduce split-K + bias + relu ----------
__global__ void k_reduce_relu(const float* __restrict__ xpart,
                              const float* __restrict__ b_conv,
                              float* __restrict__ xbuf) {
    const int f = blockIdx.x * blockDim.x + threadIdx.x;
    if (f >= IN_CH * NPOS) return;
    const int o = f / NPOS;
    float s = b_conv[o];
#pragma unroll
    for (int cs = 0; cs < CSPLIT; cs++) s += xpart[(size_t)cs * IN_CH * NPOS + f];
    xbuf[f] = fmaxf(s, 0.f);
}

// ---------- kernel 3: 1x1 heads (cls: 9 ch, reg: 36 ch) ----------
// grid = 45 blocks, 256 threads (196 active)
__global__ __launch_bounds__(256) void k_heads(const float* __restrict__ xbuf,
                                               const float* __restrict__ w_cls,
                                               const float* __restrict__ b_cls,
                                               const float* __restrict__ w_reg,
                                               const float* __restrict__ b_reg,
                                               float* __restrict__ cls_plane,
                                               float* __restrict__ reg_plane) {
    const int ch = blockIdx.x;
    const int p = threadIdx.x;
    if (p >= NPOS) return;
    const float* w;
    float b;
    float* out;
    if (ch < NA) { w = w_cls + (size_t)ch * IN_CH; b = b_cls[ch]; out = cls_plane + ch * NPOS; }
    else { const int r = ch - NA; w = w_reg + (size_t)r * IN_CH; b = b_reg[r]; out = reg_plane + r * NPOS; }
    float acc = 0.f;
#pragma unroll 4
    for (int c = 0; c < IN_CH; c++) acc += xbuf[(size_t)c * NPOS + p] * w[c];
    out[p] = acc + b;
}

// ---------- kernel 4: decode + sigmoid + exact top-1000 (bitonic) ----------
// 1 block, 1024 threads
__global__ __launch_bounds__(1024) void k_sort_top(const float* __restrict__ cls_plane,
                                                   const float* __restrict__ reg_plane,
                                                   float* __restrict__ boxes1000,
                                                   float* __restrict__ scores1000,
                                                   unsigned long long* __restrict__ validmask) {
    __shared__ unsigned long long keys[2048];          // 16 KB
    __shared__ float props[NANCH][4];                  // 28.2 KB
    const int tid = threadIdx.x;

    for (int i = tid; i < 2048; i += 1024) {
        unsigned long long key = 0ull;
        if (i < NANCH) {
            const int p = i / NA, a = i % NA;
            const int yy = p / FW, xx = p % FW;
            const int r = a / 3, s = a % 3;
            const float scv = (s == 0) ? 128.f : ((s == 1) ? 256.f : 512.f);
            const float rat = (r == 0) ? 0.5f : ((r == 1) ? 1.0f : 2.0f);
            const float hr = sqrtf(rat), wr = 1.0f / hr;
            const float wsv = wr * scv, hsv = hr * scv;
            const float sxf = (float)(xx * 16), syf = (float)(yy * 16);
            const float ax0 = sxf + rintf(-0.5f * wsv);
            const float ay0 = syf + rintf(-0.5f * hsv);
            const float ax1 = sxf + rintf(0.5f * wsv);
            const float ay1 = syf + rintf(0.5f * hsv);
            const float w = ax1 - ax0, h = ay1 - ay0;
            const float cx = ax0 + 0.5f * w, cy = ay0 + 0.5f * h;
            const float dx = reg_plane[(a * 4 + 0) * NPOS + p];
            const float dy = reg_plane[(a * 4 + 1) * NPOS + p];
            const float dw = fminf(reg_plane[(a * 4 + 2) * NPOS + p], BBOX_CLIP);
            const float dh = fminf(reg_plane[(a * 4 + 3) * NPOS + p], BBOX_CLIP);
            const float pcx = dx * w + cx, pcy = dy * h + cy;
            const float pw = expf(dw) * w, ph = expf(dh) * h;
            props[i][0] = pcx - 0.5f * pw;
            props[i][1] = pcy - 0.5f * ph;
            props[i][2] = pcx + 0.5f * pw;
            props[i][3] = pcy + 0.5f * ph;
            const float sc = cls_plane[a * NPOS + p];
            const float prob = 1.0f / (1.0f + expf(-sc));
            key = ((unsigned long long)(__float_as_uint(prob) | 0x80000000u) << 32)
                | (unsigned long long)(0xFFFFFFFFu - (unsigned)i);
        }
        keys[i] = key;
    }

    // bitonic sort, descending
    for (int k = 2; k <= 2048; k <<= 1) {
        for (int jj = k >> 1; jj > 0; jj >>= 1) {
            __syncthreads();
            for (int t = tid; t < 2048; t += 1024) {
                const int ixj = t ^ jj;
                if (ixj > t) {
                    const unsigned long long A = keys[t], B = keys[ixj];
                    const bool up = ((t & k) == 0);
                    const bool sw = up ? (A < B) : (A > B);
                    if (sw) { keys[t] = B; keys[ixj] = A; }
                }
            }
        }
    }
    __syncthreads();

    bool invalid = false;
    if (tid < K1) {
        const unsigned long long key = keys[tid];
        const unsigned idx = 0xFFFFFFFFu - (unsigned)(key & 0xFFFFFFFFull);
        const float prob = __uint_as_float((unsigned)(key >> 32) & 0x7FFFFFFFu);
        const float b0 = fminf(fmaxf(props[idx][0], 0.f), IMG_W);
        const float b1 = fminf(fmaxf(props[idx][1], 0.f), IMG_H);
        const float b2 = fminf(fmaxf(props[idx][2], 0.f), IMG_W);
        const float b3 = fminf(fmaxf(props[idx][3], 0.f), IMG_H);
        const float bw = b2 - b0, bh = b3 - b1;
        invalid = !(bw >= 16.f && bh >= 16.f);
        boxes1000[tid * 4 + 0] = b0; boxes1000[tid * 4 + 1] = b1;
        boxes1000[tid * 4 + 2] = b2; boxes1000[tid * 4 + 3] = b3;
        scores1000[tid] = prob;
    }
    const unsigned long long inv = __ballot(invalid);
    if ((tid & 63) == 0 && (tid >> 6) < 16) validmask[tid >> 6] = inv;
}

// ---------- kernel 5: IoU suppression bitmask ----------
// grid = 1000 blocks, 1024 threads
__global__ __launch_bounds__(1024) void k_iou_mask(const float* __restrict__ boxes1000,
                                                   unsigned long long* __restrict__ mask) {
    const int i = blockIdx.x;
    const int j = threadIdx.x;
    const float ix0 = boxes1000[i * 4 + 0], iy0 = boxes1000[i * 4 + 1];
    const float ix1 = boxes1000[i * 4 + 2], iy1 = boxes1000[i * 4 + 3];
    const float areai = (ix1 - ix0) * (iy1 - iy0);
    bool pred = false;
    if (j < K1 && j > i) {
        const float jx0 = boxes1000[j * 4 + 0], jy0 = boxes1000[j * 4 + 1];
        const float jx1 = boxes1000[j * 4 + 2], jy1 = boxes1000[j * 4 + 3];
        const float areaj = (jx1 - jx0) * (jy1 - jy0);
        const float xx0 = fmaxf(ix0, jx0), yy0 = fmaxf(iy0, jy0);
        const float xx1 = fminf(ix1, jx1), yy1 = fminf(iy1, jy1);
        const float w = fmaxf(xx1 - xx0, 0.f), h = fmaxf(yy1 - yy0, 0.f);
        const float inter = w * h;
        const float uni = areai + areaj - inter;
        const float iou = (uni > 0.f) ? inter / uni : 0.f;
        pred = iou > 0.7f;
    }
    const unsigned long long m = __ballot(pred);
    if ((j & 63) == 0) mask[(size_t)i * 16 + (j >> 6)] = m;
}

// ---------- kernel 6: sequential NMS scan + masked top-300 + output ----------
// 1 block, 1024 threads
__global__ __launch_bounds__(1024) void k_final(const unsigned long long* __restrict__ mask,
                                                const unsigned long long* __restrict__ validmask,
                                                const float* __restrict__ boxes1000,
                                                const float* __restrict__ scores1000,
                                                float* __restrict__ out) {
    __shared__ unsigned long long keys[1024];      // 8 KB
    __shared__ unsigned long long diag[1024];      // 8 KB (mask[i][i>>6])
    __shared__ unsigned long long removed_s[16];
    const int tid = threadIdx.x;

    for (int i = tid; i < K1; i += 1024) diag[i] = mask[(size_t)i * 16 + (i >> 6)];
    __syncthreads();

    // wave 0: 16 lanes own removal words; cur tracks the active word (uniform)
    if (tid < 64) {
        const int lane = tid;
        unsigned long long remv = (lane < 16) ? validmask[lane] : 0ull;
        for (int wword = 0; wword < 16; wword++) {
            unsigned long long cur = __shfl(remv, wword);
            const int bbase = wword * 64;
            const int nb = (K1 - bbase < 64) ? (K1 - bbase) : 64;
#pragma unroll 8
            for (int b = 0; b < nb; b++) {
                const int i = bbase + b;
                const unsigned long long m_lane = mask[(size_t)i * 16 + (lane & 15)];
                const unsigned long long m_w = diag[i];
                const bool kept = ((cur >> b) & 1ull) == 0ull;
                remv |= kept ? m_lane : 0ull;
                cur  |= kept ? m_w : 0ull;
            }
        }
        if (lane < 16) removed_s[lane] = remv;
    }
    __syncthreads();

    {
        const int j = tid;
        unsigned long long key = 0ull;
        if (j < K1) {
            const bool rem = (removed_s[j >> 6] >> (j & 63)) & 1ull;
            const float m = rem ? -1.0f : scores1000[j];
            key = ((unsigned long long)f2sort(m) << 32)
                | (unsigned long long)(0xFFFFFFFFu - (unsigned)j);
        }
        keys[j] = key;
    }

    for (int k = 2; k <= 1024; k <<= 1) {
        for (int jj = k >> 1; jj > 0; jj >>= 1) {
            __syncthreads();
            const int t = tid;
            const int ixj = t ^ jj;
            if (ixj > t) {
                const unsigned long long A = keys[t], B = keys[ixj];
                const bool up = ((t & k) == 0);
                const bool sw = up ? (A < B) : (A > B);
                if (sw) { keys[t] = B; keys[ixj] = A; }
            }
        }
    }
    __syncthreads();

    if (tid < TOPK_N) {
        const unsigned long long key = keys[tid];
        const float sc = sort2f((unsigned)(key >> 32));
        const unsigned j = 0xFFFFFFFFu - (unsigned)(key & 0xFFFFFFFFull);
        float o0 = 0.f, o1 = 0.f, o2 = 0.f, o3 = 0.f, os = 0.f;
        if (sc > 0.f) {
            o0 = boxes1000[j * 4 + 0]; o1 = boxes1000[j * 4 + 1];
            o2 = boxes1000[j * 4 + 2]; o3 = boxes1000[j * 4 + 3];
            os = sc;
        }
        out[tid * 4 + 0] = o0; out[tid * 4 + 1] = o1;
        out[tid * 4 + 2] = o2; out[tid * 4 + 3] = o3;
        out[1200 + tid] = os;
    }
}

// ---------- launcher ----------
extern "C" void kernel_launch(void* const* d_in, const int* in_sizes, int n_in,
                              void* d_out, int out_size, void* d_ws, size_t ws_size,
                              hipStream_t stream) {
    const float* feature = (const float*)d_in[1];
    const float* w_conv  = (const float*)d_in[2];
    const float* b_conv  = (const float*)d_in[3];
    const float* w_cls   = (const float*)d_in[4];
    const float* b_cls   = (const float*)d_in[5];
    const float* w_reg   = (const float*)d_in[6];
    const float* b_reg   = (const float*)d_in[7];
    float* out = (float*)d_out;

    char* w = (char*)d_ws;
    float* xpart = (float*)(w + 0);                       // 8*768*196*4 = 4,816,896 B
    float* xbuf  = (float*)(w + 4816896);                 // 602,112 B
    float* cls_p = (float*)(w + 5419008);                 // 7,056 B
    float* reg_p = (float*)(w + 5426064);                 // 28,224 B
    float* boxes = (float*)(w + 5454288);                 // 16,000 B
    float* scrs  = (float*)(w + 5470288);                 // 4,000 B
    unsigned long long* vmask = (unsigned long long*)(w + 5474288);  // 128 B
    unsigned long long* mask  = (unsigned long long*)(w + 5474416);  // 128,000 B

    k_conv<<<(IN_CH / OPB) * CSPLIT, 256, 0, stream>>>(feature, w_conv, xpart);
    k_reduce_relu<<<(IN_CH * NPOS + 255) / 256, 256, 0, stream>>>(xpart, b_conv, xbuf);
    k_heads<<<NA + 4 * NA, 256, 0, stream>>>(xbuf, w_cls, b_cls, w_reg, b_reg, cls_p, reg_p);
    k_sort_top<<<1, 1024, 0, stream>>>(cls_p, reg_p, boxes, scrs, vmask);
    k_iou_mask<<<K1, 1024, 0, stream>>>(boxes, mask);
    k_final<<<1, 1024, 0, stream>>>(mask, vmask, boxes, scrs, out);
}